// Round 3
// baseline (96.450 us; speedup 1.0000x reference)
//
#include <hip/hip_runtime.h>
#include <hip/hip_bf16.h>

// KAN conv: 8x KANLinear(9->1) over 3x3 patches, 256 images of 64x64.
// Phase 1: per-pixel features (silu + 8 cubic B-spline bases) -> LDS SoA
//          planes feat[j][18][68] (pitch 68 => 16B-aligned rows).
//          Uniform knots => only 4 nonzero bases, closed-form segments.
// Phase 2: per thread 4 consecutive output cols x 8 convs; weights folded
//          (prep kernel) into 128B-aligned 32-float chunks per (ky,n) so
//          the compiler emits batched s_load_dwordx16 (2 per (ky,n)).

#define N_CONVS 8
#define HH 64
#define WW 64
#define HO 62
#define WO 62
#define BAND 16
#define LROWS 18
#define PW 68                   // plane row pitch (floats), multiple of 4
#define PLANE (LROWS * PW)      // 1224 floats per feature plane

// wf layout: [ky][n][32] floats; chunk = {kx0:10, kx1:10, kx2:10, pad:2},
// each 10 = {bw[n][i], sc*sw[n][i][0..7], 0}, i = ky*3+kx.
__global__ __launch_bounds__(768) void kan_prep(const float* __restrict__ bw,
                                                const float* __restrict__ sw,
                                                const float* __restrict__ sc,
                                                float* __restrict__ wf) {
    const int t   = threadIdx.x;        // 0..767
    const int blk = t >> 5;             // ky*8+n
    const int r   = t & 31;
    const int ky  = blk >> 3, n = blk & 7;
    const int kx  = r / 10, j = r % 10;
    float v = 0.0f;
    if (kx < 3 && j <= 8) {
        const int i = ky * 3 + kx;
        v = (j == 0) ? bw[n * 9 + i]
                     : sw[(n * 9 + i) * 8 + (j - 1)] * sc[n * 9 + i];
    }
    wf[t] = v;
}

__global__ __launch_bounds__(256, 3) void kan_main(
    const float* __restrict__ x,     // [256,64,64]
    const float* __restrict__ grid,  // first row: 12 uniform knots
    const float* __restrict__ wf,    // folded weights (768 floats)
    float* __restrict__ out)         // [256*8,62,62]
{
    __shared__ __align__(16) float feat[9 * PLANE];

    const int blk  = blockIdx.x;
    const int band = blk & 3;
    const int img  = blk >> 2;
    const int r0   = band * BAND;
    const int nr   = (HO - r0) < BAND ? (HO - r0) : BAND;      // 16,16,16,14
    const int nin  = (HH - r0) < LROWS ? (HH - r0) : LROWS;    // 18,18,18,16

    const float g0   = grid[0];
    const float invh = __builtin_amdgcn_rcpf(grid[1] - grid[0]);

    // ---- Phase 1: per-pixel features into SoA planes ----
    const float* xb = x + (size_t)img * (HH * WW) + (size_t)r0 * WW;
    for (int p = threadIdx.x; p < nin * WW; p += 256) {
        const int r = p >> 6, c = p & 63;
        const float xv = xb[p];

        float* fp = &feat[r * PW + c];
        fp[0] = xv * __builtin_amdgcn_rcpf(1.0f + __expf(-xv));  // silu
#pragma unroll
        for (int j = 1; j < 9; j++) fp[j * PLANE] = 0.0f;

        const float u0 = (xv - g0) * invh;
        const int   m  = (int)floorf(u0);
        if (m >= 0 && m <= 10) {
            const float u  = u0 - (float)m;
            const float um = 1.0f - u;
            const float u2 = u * u, u3 = u2 * u;
            const float N0 = um * um * um * (1.0f / 6.0f);
            const float N1 = (3.0f * u3 - 6.0f * u2 + 4.0f) * (1.0f / 6.0f);
            const float N2 = (-3.0f * u3 + 3.0f * u2 + 3.0f * u + 1.0f) * (1.0f / 6.0f);
            const float N3 = u3 * (1.0f / 6.0f);
            const float Nv[4] = {N0, N1, N2, N3};
            // B_j nonzero for j = m-3..m (within 0..7); B_{m-3+s} = Nv[s]
#pragma unroll
            for (int s = 0; s < 4; s++) {
                const int j = m - 3 + s;
                if (j >= 0 && j <= 7) fp[(j + 1) * PLANE] = Nv[s];
            }
        }
    }
    __syncthreads();

    // ---- Phase 2: 4 consecutive output cols x 8 convs per thread ----
    const int row = threadIdx.x >> 4;
    const int xs  = (threadIdx.x & 15) << 2;
    if (row < nr) {
        float acc[N_CONVS][4];
#pragma unroll
        for (int n = 0; n < N_CONVS; n++)
#pragma unroll
            for (int t = 0; t < 4; t++) acc[n][t] = 0.0f;

#pragma unroll 1
        for (int ky = 0; ky < 3; ky++) {
            float fw[9][6];
#pragma unroll
            for (int j = 0; j < 9; j++) {
                const float* pl = &feat[j * PLANE + (row + ky) * PW + xs];
                const float4 a = *(const float4*)pl;        // 16B-aligned
                const float2 b = *(const float2*)(pl + 4);
                fw[j][0] = a.x; fw[j][1] = a.y; fw[j][2] = a.z;
                fw[j][3] = a.w; fw[j][4] = b.x; fw[j][5] = b.y;
            }
            const float* wk = wf + (ky << 8);               // ky*8*32
#pragma unroll
            for (int n = 0; n < N_CONVS; n++) {
                const float* wn = wk + (n << 5);            // uniform -> SGPR
#pragma unroll
                for (int kx = 0; kx < 3; kx++) {
                    const float* gg = wn + kx * 10;
#pragma unroll
                    for (int t = 0; t < 4; t++) {
                        float a = acc[n][t];
#pragma unroll
                        for (int j = 0; j < 9; j++)
                            a = fmaf(gg[j], fw[j][kx + t], a);
                        acc[n][t] = a;
                    }
                }
            }
        }

        const int oy = r0 + row;
        float* ob = out + (size_t)img * N_CONVS * (HO * WO) + oy * WO + xs;
#pragma unroll
        for (int n = 0; n < N_CONVS; n++) {
            float* o = ob + n * (HO * WO);
            *(float2*)o = make_float2(acc[n][0], acc[n][1]);
            if (xs < 58) *(float2*)(o + 2) = make_float2(acc[n][2], acc[n][3]);
        }
    }
}

extern "C" void kernel_launch(void* const* d_in, const int* in_sizes, int n_in,
                              void* d_out, int out_size, void* d_ws, size_t ws_size,
                              hipStream_t stream) {
    const float* x    = (const float*)d_in[0];
    const float* bw   = (const float*)d_in[1];
    const float* sw   = (const float*)d_in[2];
    const float* sc   = (const float*)d_in[3];
    const float* grid = (const float*)d_in[4];
    float* out = (float*)d_out;
    float* wf  = (float*)d_ws;

    kan_prep<<<1, 768, 0, stream>>>(bw, sw, sc, wf);
    kan_main<<<256 * 4, 256, 0, stream>>>(x, grid, wf, out);
}

// Round 4
// 87.561 us; speedup vs baseline: 1.1015x; 1.1015x over previous
//
#include <hip/hip_runtime.h>
#include <hip/hip_bf16.h>

// KAN conv: 8x KANLinear(9->1) over 3x3 patches, 256 images of 64x64.
// R3: occupancy experiment. BAND 16->8 (LDS 42->23 KB), 2 px/thread,
// launch_bounds(256,5) -> ~20 waves/CU (vs 12). Work conserved; this
// isolates whether the kernel is latency/occupancy-bound (Model A).
//
// Phase 1: per-pixel features (silu + 8 cubic B-spline bases, closed-form
//          uniform-knot segments) -> LDS SoA planes feat[9][10][66].
// Phase 2: per thread 2 consecutive output cols x 8 convs; folded weights
//          (prep kernel) read via uniform s_loads from d_ws.

#define N_CONVS 8
#define HH 64
#define WW 64
#define HO 62
#define WO 62
#define BAND 8
#define LROWS 10                // BAND + 2
#define PW 66                   // plane row pitch (floats), even -> 8B rows
#define PLANE (LROWS * PW)      // 660 floats per feature plane

// wf layout: [ky][n][32] floats; chunk = {kx0:10, kx1:10, kx2:10, pad:2},
// each 10 = {bw[n][i], sc*sw[n][i][0..7], 0}, i = ky*3+kx.
__global__ __launch_bounds__(768) void kan_prep(const float* __restrict__ bw,
                                                const float* __restrict__ sw,
                                                const float* __restrict__ sc,
                                                float* __restrict__ wf) {
    const int t   = threadIdx.x;        // 0..767
    const int blk = t >> 5;             // ky*8+n
    const int r   = t & 31;
    const int ky  = blk >> 3, n = blk & 7;
    const int kx  = r / 10, j = r % 10;
    float v = 0.0f;
    if (kx < 3 && j <= 8) {
        const int i = ky * 3 + kx;
        v = (j == 0) ? bw[n * 9 + i]
                     : sw[(n * 9 + i) * 8 + (j - 1)] * sc[n * 9 + i];
    }
    wf[t] = v;
}

__global__ __launch_bounds__(256, 5) void kan_main(
    const float* __restrict__ x,     // [256,64,64]
    const float* __restrict__ grid,  // first row: 12 uniform knots
    const float* __restrict__ wf,    // folded weights (768 floats)
    float* __restrict__ out)         // [256*8,62,62]
{
    __shared__ __align__(16) float feat[9 * PLANE];

    const int blk  = blockIdx.x;
    const int band = blk & 7;            // 8 bands of 8 output rows
    const int img  = blk >> 3;
    const int r0   = band * BAND;
    const int nr   = (HO - r0) < BAND  ? (HO - r0) : BAND;    // 8 (band7: 6)
    const int nin  = (HH - r0) < LROWS ? (HH - r0) : LROWS;   // 10 (band7: 8)

    const float g0   = grid[0];
    const float invh = __builtin_amdgcn_rcpf(grid[1] - grid[0]);

    // ---- Phase 1: per-pixel features into SoA planes ----
    const float* xb = x + (size_t)img * (HH * WW) + (size_t)r0 * WW;
    for (int p = threadIdx.x; p < nin * WW; p += 256) {
        const int r = p >> 6, c = p & 63;
        const float xv = xb[p];

        float* fp = &feat[r * PW + c];
        fp[0] = xv * __builtin_amdgcn_rcpf(1.0f + __expf(-xv));  // silu
#pragma unroll
        for (int j = 1; j < 9; j++) fp[j * PLANE] = 0.0f;

        const float u0 = (xv - g0) * invh;
        const int   m  = (int)floorf(u0);
        if (m >= 0 && m <= 10) {
            const float u  = u0 - (float)m;
            const float um = 1.0f - u;
            const float u2 = u * u, u3 = u2 * u;
            const float N0 = um * um * um * (1.0f / 6.0f);
            const float N1 = (3.0f * u3 - 6.0f * u2 + 4.0f) * (1.0f / 6.0f);
            const float N2 = (-3.0f * u3 + 3.0f * u2 + 3.0f * u + 1.0f) * (1.0f / 6.0f);
            const float N3 = u3 * (1.0f / 6.0f);
            const float Nv[4] = {N0, N1, N2, N3};
            // B_j nonzero for j = m-3..m (within 0..7); B_{m-3+s} = Nv[s]
#pragma unroll
            for (int s = 0; s < 4; s++) {
                const int j = m - 3 + s;
                if (j >= 0 && j <= 7) fp[(j + 1) * PLANE] = Nv[s];
            }
        }
    }
    __syncthreads();

    // ---- Phase 2: 2 consecutive output cols x 8 convs per thread ----
    const int row = threadIdx.x >> 5;          // 0..7
    const int xs  = (threadIdx.x & 31) << 1;   // 0,2,..,62 (62 invalid)
    if (row < nr && xs < WO) {
        float acc[N_CONVS][2];
#pragma unroll
        for (int n = 0; n < N_CONVS; n++) { acc[n][0] = 0.0f; acc[n][1] = 0.0f; }

#pragma unroll 1
        for (int ky = 0; ky < 3; ky++) {
            float fw[9][4];
#pragma unroll
            for (int j = 0; j < 9; j++) {
                const float* pl = &feat[j * PLANE + (row + ky) * PW + xs];
                const float2 a = *(const float2*)pl;       // 8B-aligned
                const float2 b = *(const float2*)(pl + 2);
                fw[j][0] = a.x; fw[j][1] = a.y; fw[j][2] = b.x; fw[j][3] = b.y;
            }
            const float* wk = wf + (ky << 8);              // ky*8*32
#pragma unroll
            for (int n = 0; n < N_CONVS; n++) {
                const float* wn = wk + (n << 5);           // uniform -> s_load
#pragma unroll
                for (int kx = 0; kx < 3; kx++) {
                    const float* gg = wn + kx * 10;
#pragma unroll
                    for (int t = 0; t < 2; t++) {
                        float a = acc[n][t];
#pragma unroll
                        for (int j = 0; j < 9; j++)
                            a = fmaf(gg[j], fw[j][kx + t], a);
                        acc[n][t] = a;
                    }
                }
            }
        }

        const int oy = r0 + row;
        float* ob = out + (size_t)img * N_CONVS * (HO * WO) + oy * WO + xs;
#pragma unroll
        for (int n = 0; n < N_CONVS; n++)
            *(float2*)(ob + n * (HO * WO)) = make_float2(acc[n][0], acc[n][1]);
    }
}

extern "C" void kernel_launch(void* const* d_in, const int* in_sizes, int n_in,
                              void* d_out, int out_size, void* d_ws, size_t ws_size,
                              hipStream_t stream) {
    const float* x    = (const float*)d_in[0];
    const float* bw   = (const float*)d_in[1];
    const float* sw   = (const float*)d_in[2];
    const float* sc   = (const float*)d_in[3];
    const float* grid = (const float*)d_in[4];
    float* out = (float*)d_out;
    float* wf  = (float*)d_ws;

    kan_prep<<<1, 768, 0, stream>>>(bw, sw, sc, wf);
    kan_main<<<256 * 8, 256, 0, stream>>>(x, grid, wf, out);
}